// Round 3
// baseline (485.468 us; speedup 1.0000x reference)
//
#include <hip/hip_runtime.h>
#include <math.h>

// clDice loss on 32x1x512x512: sigmoid + dice + 10x soft-skeletonize + skel dice.
// R1: removed contended double atomics -> per-block partials (1059 -> 466 us).
// R3: fuse 2 skeletonize iterations per kernel via two-stage LDS (A: input 72x72 halo,
//     B: iter1 on 68x72), fuse sigmoid+dice into k_first, fuse skel-dice partials into
//     k_last (pred+target tiles in one block, no final write). 13 -> 7 dispatches,
//     ~1.47 GB -> ~0.72 GB traffic.

#define H 512
#define W 512
#define IMG (H * W)
#define NIMG 64
#define NPRED 32

#define APITCH 80          // 1 pad quad + 18 loaded quads + 1 pad quad
#define AROWS 76           // 2 pad + 72 loaded + 2 pad ; A row r <-> global tileY + r - 6
#define BPITCH 72          // 18 quads <-> global cols tileX-4 .. tileX+67
#define BROWS 68           // global rows tileY-2 .. tileY+65

__device__ __forceinline__ float wsum64(float v) {
#pragma unroll
    for (int o = 32; o > 0; o >>= 1) v += __shfl_down(v, o);
    return v;
}

// hmin (3-wide row min) for 6 positions; h[j] <-> col base-1+j, via 3 aligned b128 reads.
__device__ __forceinline__ void hmin3(const float* __restrict__ row, float h[6]) {
    float4 q0 = *(const float4*)(row);
    float4 q1 = *(const float4*)(row + 4);
    float4 q2 = *(const float4*)(row + 8);
    h[0] = fminf(q0.z, fminf(q0.w, q1.x));
    h[1] = fminf(q0.w, fminf(q1.x, q1.y));
    h[2] = fminf(q1.x, fminf(q1.y, q1.z));
    h[3] = fminf(q1.y, fminf(q1.z, q1.w));
    h[4] = fminf(q1.z, fminf(q1.w, q2.x));
    h[5] = fminf(q1.w, fminf(q2.x, q2.y));
}

// e[j] = eroded value; -inf at out-of-image positions (dilation-neutral).
__device__ __forceinline__ void erode1(const float a[6], const float b[6], const float c[6],
                                       bool rowok, const bool cm[6], float e[6]) {
#pragma unroll
    for (int j = 0; j < 6; j++) {
        float v = fminf(a[j], fminf(b[j], c[j]));
        e[j] = (rowok && cm[j]) ? v : -INFINITY;
    }
}

__device__ __forceinline__ void erode2(const float a[6], const float b[6], const float c[6],
                                       int gy, bool lo, bool ro, float e[6]) {
    bool oob = (gy < 0) || (gy >= H);
#pragma unroll
    for (int j = 0; j < 6; j++) {
        float v = fminf(a[j], fminf(b[j], c[j]));
        e[j] = oob ? -INFINITY : v;
    }
    if (lo) e[0] = -INFINITY;
    if (ro) e[5] = -INFINITY;
}

__device__ __forceinline__ void hmax1(const float e[6], float hx[4], float ec[4]) {
    hx[0] = fmaxf(e[0], fmaxf(e[1], e[2]));
    hx[1] = fmaxf(e[1], fmaxf(e[2], e[3]));
    hx[2] = fmaxf(e[2], fmaxf(e[3], e[4]));
    hx[3] = fmaxf(e[3], fmaxf(e[4], e[5]));
    ec[0] = e[1]; ec[1] = e[2]; ec[2] = e[3]; ec[3] = e[4];
}

// Fill LDS A (76x80) from src: loaded region rows 2..73 (global -4..67), quads 1..18
// (global cols -4..67); everything else (+ out-of-image) = +inf. SIG: apply sigmoid.
template<int SIG>
__device__ void fillA(float* __restrict__ A, const float* __restrict__ src,
                      int tileX, int tileY, int tid) {
    const float PINF = INFINITY;
    for (int it = tid; it < AROWS * 20; it += 128) {
        int r = it / 20;
        int c = it - r * 20;
        int gy = tileY + r - 6;
        int gx = tileX + 4 * c - 8;
        float4 v = make_float4(PINF, PINF, PINF, PINF);
        if (r >= 2 && r <= 73 && (unsigned)(c - 1) < 18u &&
            (unsigned)gy < (unsigned)H && (unsigned)gx < (unsigned)W) {
            v = *(const float4*)(src + (size_t)gy * W + gx);
            if (SIG) {
                v.x = 1.0f / (1.0f + __expf(-v.x));
                v.y = 1.0f / (1.0f + __expf(-v.y));
                v.z = 1.0f / (1.0f + __expf(-v.z));
                v.w = 1.0f / (1.0f + __expf(-v.w));
            }
        }
        *(float4*)(A + r * APITCH + 4 * c) = v;
    }
}

// Stage 1: one skeletonize iteration A -> B on rows -2..65, quads -4..67 (outer 2 cols
// of edge quads are garbage-by-contract, never consumed). 144 items (18 quads x 8
// strips of 9 rows covering -4..67; rows outside B skipped at store).
__device__ void stage1(const float* __restrict__ A, float* __restrict__ B,
                       int tileX, int tileY, int tid) {
    for (int item = tid; item < 144; item += 128) {
        const int strip = item / 18;
        const int q = item - strip * 18;
        const int gcb = tileX - 4 + 4 * q;       // output quad base col (global)
        const int ys = tileY - 4 + 9 * strip;    // first output row (global)
        bool cm[6], sm[4];
#pragma unroll
        for (int j = 0; j < 6; j++) cm[j] = ((unsigned)(gcb - 1 + j) < (unsigned)W);
#pragma unroll
        for (int j = 0; j < 4; j++) sm[j] = ((unsigned)(gcb + j) < (unsigned)W);
        const int lr0 = ys - tileY + 6;          // A-local row of ys
        const float* Ab = A + 4 * q;
        float hm[3][6], hx[3][4], e[6], ec_cur[4], ec_nxt[4];
        hmin3(Ab + (lr0 - 2) * APITCH, hm[0]);
        hmin3(Ab + (lr0 - 1) * APITCH, hm[1]);
        hmin3(Ab + (lr0 + 0) * APITCH, hm[2]);
        erode1(hm[0], hm[1], hm[2], (unsigned)(ys - 1) < (unsigned)H, cm, e);
        hmax1(e, hx[0], ec_nxt);
        hmin3(Ab + (lr0 + 1) * APITCH, hm[0]);
        erode1(hm[1], hm[2], hm[0], (unsigned)ys < (unsigned)H, cm, e);
        hmax1(e, hx[1], ec_cur);
#pragma unroll
        for (int k = 0; k < 9; k++) {
            hmin3(Ab + (lr0 + 2 + k) * APITCH, hm[(k + 1) % 3]);
            erode1(hm[(k + 2) % 3], hm[k % 3], hm[(k + 1) % 3],
                   (unsigned)(ys + k + 1) < (unsigned)H, cm, e);
            hmax1(e, hx[(k + 2) % 3], ec_nxt);
            float t0 = fmaxf(hx[k % 3][0], fmaxf(hx[(k + 1) % 3][0], hx[(k + 2) % 3][0]));
            float t1 = fmaxf(hx[k % 3][1], fmaxf(hx[(k + 1) % 3][1], hx[(k + 2) % 3][1]));
            float t2 = fmaxf(hx[k % 3][2], fmaxf(hx[(k + 1) % 3][2], hx[(k + 2) % 3][2]));
            float t3 = fmaxf(hx[k % 3][3], fmaxf(hx[(k + 1) % 3][3], hx[(k + 2) % 3][3]));
            float4 sc = *(const float4*)(A + (lr0 + k) * APITCH + 4 * q + 4);
            float o0 = fminf(fmaxf(sc.x - (sc.x - ec_cur[0]) * t0, 0.0f), 1.0f);
            float o1 = fminf(fmaxf(sc.y - (sc.y - ec_cur[1]) * t1, 0.0f), 1.0f);
            float o2 = fminf(fmaxf(sc.z - (sc.z - ec_cur[2]) * t2, 0.0f), 1.0f);
            float o3 = fminf(fmaxf(sc.w - (sc.w - ec_cur[3]) * t3, 0.0f), 1.0f);
            int gy = ys + k;
            int br = gy - tileY + 2;
            if (br >= 0 && br < BROWS) {
                bool rin = ((unsigned)gy < (unsigned)H);
                float4 ov;
                ov.x = (rin && sm[0]) ? o0 : INFINITY;  // +inf outside image: erosion-neutral
                ov.y = (rin && sm[1]) ? o1 : INFINITY;
                ov.z = (rin && sm[2]) ? o2 : INFINITY;
                ov.w = (rin && sm[3]) ? o3 : INFINITY;
                *(float4*)(B + br * BPITCH + 4 * q) = ov;
            }
            ec_cur[0] = ec_nxt[0]; ec_cur[1] = ec_nxt[1];
            ec_cur[2] = ec_nxt[2]; ec_cur[3] = ec_nxt[3];
        }
    }
}

// Stage 2: second iteration B -> interior 64x64 (to global or to registers).
template<bool TOREG>
__device__ void stage2(const float* __restrict__ B, int tileX, int tileY,
                       int tx, int ty, float* __restrict__ gdst, float (*oreg)[4]) {
    const int X = tileX + 4 * tx;
    const int gy0 = tileY + ty * 8;
    const int rb = ty * 8 + 2;                   // B-local row of gy0
    const bool lo = (X == 0);
    const bool ro = (X + 4 >= W);
    const float* Bb = B + 4 * tx;
    float hm[3][6], hx[3][4], e[6], ec_cur[4], ec_nxt[4];
    hmin3(Bb + (rb - 2) * BPITCH, hm[0]);
    hmin3(Bb + (rb - 1) * BPITCH, hm[1]);
    hmin3(Bb + (rb + 0) * BPITCH, hm[2]);
    erode2(hm[0], hm[1], hm[2], gy0 - 1, lo, ro, e);
    hmax1(e, hx[0], ec_nxt);
    hmin3(Bb + (rb + 1) * BPITCH, hm[0]);
    erode2(hm[1], hm[2], hm[0], gy0, lo, ro, e);
    hmax1(e, hx[1], ec_cur);
#pragma unroll
    for (int k = 0; k < 8; k++) {
        hmin3(Bb + (rb + 2 + k) * BPITCH, hm[(k + 1) % 3]);
        erode2(hm[(k + 2) % 3], hm[k % 3], hm[(k + 1) % 3], gy0 + k + 1, lo, ro, e);
        hmax1(e, hx[(k + 2) % 3], ec_nxt);
        float t0 = fmaxf(hx[k % 3][0], fmaxf(hx[(k + 1) % 3][0], hx[(k + 2) % 3][0]));
        float t1 = fmaxf(hx[k % 3][1], fmaxf(hx[(k + 1) % 3][1], hx[(k + 2) % 3][1]));
        float t2 = fmaxf(hx[k % 3][2], fmaxf(hx[(k + 1) % 3][2], hx[(k + 2) % 3][2]));
        float t3 = fmaxf(hx[k % 3][3], fmaxf(hx[(k + 1) % 3][3], hx[(k + 2) % 3][3]));
        float4 sc = *(const float4*)(B + (rb + k) * BPITCH + 4 * tx + 4);
        float4 o;
        o.x = fminf(fmaxf(sc.x - (sc.x - ec_cur[0]) * t0, 0.0f), 1.0f);
        o.y = fminf(fmaxf(sc.y - (sc.y - ec_cur[1]) * t1, 0.0f), 1.0f);
        o.z = fminf(fmaxf(sc.z - (sc.z - ec_cur[2]) * t2, 0.0f), 1.0f);
        o.w = fminf(fmaxf(sc.w - (sc.w - ec_cur[3]) * t3, 0.0f), 1.0f);
        if (TOREG) {
            oreg[k][0] = o.x; oreg[k][1] = o.y; oreg[k][2] = o.z; oreg[k][3] = o.w;
        } else {
            *(float4*)(gdst + (size_t)(gy0 + k) * W + X) = o;
        }
        ec_cur[0] = ec_nxt[0]; ec_cur[1] = ec_nxt[1];
        ec_cur[2] = ec_nxt[2]; ec_cur[3] = ec_nxt[3];
    }
}

// ---- K1: sigmoid + dice partials + iters 1,2 ----
__global__ __launch_bounds__(128) void k_first(
    const float* __restrict__ logits, const float* __restrict__ target,
    float* __restrict__ outb, float* __restrict__ parts0, float* __restrict__ parts1) {
    __shared__ float A[AROWS * APITCH];
    __shared__ float B[BROWS * BPITCH];
    __shared__ float red[4];
    const int img = blockIdx.z;
    const int tileX = blockIdx.x * 64, tileY = blockIdx.y * 64;
    const int tid = threadIdx.y * 16 + threadIdx.x;
    const bool pred = (img < NPRED);
    if (pred) fillA<1>(A, logits + (size_t)img * IMG, tileX, tileY, tid);
    else      fillA<0>(A, target + (size_t)(img - NPRED) * IMG, tileX, tileY, tid);
    __syncthreads();
    // dice partials over pre-skeleton interior
    float a = 0.0f, b = 0.0f;
    if (pred) {
        const float* tgt = target + (size_t)img * IMG;
        for (int i = tid; i < 1024; i += 128) {
            int r = i >> 4, c4 = (i & 15) * 4;
            float4 p = *(const float4*)(A + (r + 6) * APITCH + c4 + 8);
            float4 t = *(const float4*)(tgt + (size_t)(tileY + r) * W + tileX + c4);
            a += p.x * t.x + p.y * t.y + p.z * t.z + p.w * t.w;
            b += p.x + p.y + p.z + p.w;
        }
    } else {
        for (int i = tid; i < 1024; i += 128) {
            int r = i >> 4, c4 = (i & 15) * 4;
            float4 t = *(const float4*)(A + (r + 6) * APITCH + c4 + 8);
            a += t.x + t.y + t.z + t.w;
        }
    }
    a = wsum64(a); b = wsum64(b);
    if ((tid & 63) == 0) { red[tid >> 6] = a; red[2 + (tid >> 6)] = b; }
    __syncthreads();
    if (tid == 0) {
        int bi = blockIdx.z * 64 + blockIdx.y * 8 + blockIdx.x;
        parts0[bi] = red[0] + red[1];
        parts1[bi] = red[2] + red[3];
    }
    stage1(A, B, tileX, tileY, tid);
    __syncthreads();
    stage2<false>(B, tileX, tileY, threadIdx.x, threadIdx.y,
                  outb + (size_t)img * IMG, nullptr);
}

// ---- K2..K4: two iterations, buf -> buf ----
__global__ __launch_bounds__(128) void k_mid(
    const float* __restrict__ in, float* __restrict__ outb) {
    __shared__ float A[AROWS * APITCH];
    __shared__ float B[BROWS * BPITCH];
    const int img = blockIdx.z;
    const int tileX = blockIdx.x * 64, tileY = blockIdx.y * 64;
    const int tid = threadIdx.y * 16 + threadIdx.x;
    fillA<0>(A, in + (size_t)img * IMG, tileX, tileY, tid);
    __syncthreads();
    stage1(A, B, tileX, tileY, tid);
    __syncthreads();
    stage2<false>(B, tileX, tileY, threadIdx.x, threadIdx.y,
                  outb + (size_t)img * IMG, nullptr);
}

// ---- K5: iters 9,10 for pred tile AND matching target tile; skel-dice partials ----
__global__ __launch_bounds__(128) void k_last(
    const float* __restrict__ in, float* __restrict__ pA,
    float* __restrict__ pB, float* __restrict__ pC) {
    __shared__ float A[AROWS * APITCH];
    __shared__ float B[BROWS * BPITCH];
    __shared__ float red[6];
    const int img = blockIdx.z;                  // 0..31
    const int tileX = blockIdx.x * 64, tileY = blockIdx.y * 64;
    const int tid = threadIdx.y * 16 + threadIdx.x;
    float op[8][4], ot[8][4];
    fillA<0>(A, in + (size_t)img * IMG, tileX, tileY, tid);
    __syncthreads();
    stage1(A, B, tileX, tileY, tid);
    __syncthreads();
    stage2<true>(B, tileX, tileY, threadIdx.x, threadIdx.y, nullptr, op);
    fillA<0>(A, in + (size_t)(img + NPRED) * IMG, tileX, tileY, tid);
    __syncthreads();                              // also orders stage2 B-reads before next B-writes
    stage1(A, B, tileX, tileY, tid);
    __syncthreads();
    stage2<true>(B, tileX, tileY, threadIdx.x, threadIdx.y, nullptr, ot);
    float a = 0.0f, b = 0.0f, c = 0.0f;
#pragma unroll
    for (int k = 0; k < 8; k++)
#pragma unroll
        for (int j = 0; j < 4; j++) {
            a += op[k][j] * ot[k][j];
            b += op[k][j];
            c += ot[k][j];
        }
    a = wsum64(a); b = wsum64(b); c = wsum64(c);
    if ((tid & 63) == 0) {
        red[tid >> 6] = a; red[2 + (tid >> 6)] = b; red[4 + (tid >> 6)] = c;
    }
    __syncthreads();
    if (tid == 0) {
        int bi = img * 64 + blockIdx.y * 8 + blockIdx.x;
        pA[bi] = red[0] + red[1];
        pB[bi] = red[2] + red[3];
        pC[bi] = red[4] + red[5];
    }
}

// ---- per-image dice from 64 tile partials (1 wave per image) ----
__global__ __launch_bounds__(64) void finalize_img(
    const float* __restrict__ parts0, const float* __restrict__ parts1,
    const float* __restrict__ pA, const float* __restrict__ pB,
    const float* __restrict__ pC, float* __restrict__ dices) {
    const int i = blockIdx.x, t = threadIdx.x;
    float inter = wsum64(parts0[i * 64 + t]);
    float sp = wsum64(parts1[i * 64 + t]);
    float st = wsum64(parts0[(NPRED + i) * 64 + t]);
    float i2 = wsum64(pA[i * 64 + t]);
    float sp2 = wsum64(pB[i * 64 + t]);
    float st2 = wsum64(pC[i * 64 + t]);
    if (t == 0) {
        dices[i] = (float)((2.0 * (double)inter + 1e-5) / ((double)sp + (double)st + 1e-5));
        dices[32 + i] = (float)((2.0 * (double)i2 + 1e-5) / ((double)sp2 + (double)st2 + 1e-5));
    }
}

__global__ void finalize_out(const float* __restrict__ dices, float* __restrict__ out) {
    const int t = threadIdx.x;
    double d = 0.0, sd = 0.0;
    if (t < 32) { d = dices[t]; sd = dices[32 + t]; }
#pragma unroll
    for (int o = 32; o > 0; o >>= 1) { d += __shfl_down(d, o); sd += __shfl_down(sd, o); }
    if (t == 0) {
        d *= (1.0 / 32.0); sd *= (1.0 / 32.0);
        out[0] = (float)(0.5 * (1.0 - d) + 0.5 * (1.0 - sd));
        out[1] = (float)d;
        out[2] = (float)sd;
    }
}

extern "C" void kernel_launch(void* const* d_in, const int* in_sizes, int n_in,
                              void* d_out, int out_size, void* d_ws, size_t ws_size,
                              hipStream_t stream) {
    (void)in_sizes; (void)n_in; (void)out_size; (void)ws_size;
    const float* logits = (const float*)d_in[0];
    const float* target = (const float*)d_in[1];
    float* out = (float*)d_out;
    float* buf0 = (float*)d_ws;
    float* buf1 = buf0 + (size_t)NIMG * IMG;
    float* parts0 = buf1 + (size_t)NIMG * IMG;   // 4096
    float* parts1 = parts0 + 4096;               // 4096
    float* pA = parts1 + 4096;                   // 2048
    float* pB = pA + 2048;
    float* pC = pB + 2048;
    float* dices = pC + 2048;                    // 64

    dim3 blk(16, 8, 1);
    k_first<<<dim3(8, 8, NIMG), blk, 0, stream>>>(logits, target, buf0, parts0, parts1);
    k_mid<<<dim3(8, 8, NIMG), blk, 0, stream>>>(buf0, buf1);   // iters 3,4
    k_mid<<<dim3(8, 8, NIMG), blk, 0, stream>>>(buf1, buf0);   // iters 5,6
    k_mid<<<dim3(8, 8, NIMG), blk, 0, stream>>>(buf0, buf1);   // iters 7,8
    k_last<<<dim3(8, 8, NPRED), blk, 0, stream>>>(buf1, pA, pB, pC);  // iters 9,10 + partials
    finalize_img<<<32, 64, 0, stream>>>(parts0, parts1, pA, pB, pC, dices);
    finalize_out<<<1, 64, 0, stream>>>(dices, out);
}

// Round 5
// 315.671 us; speedup vs baseline: 1.5379x; 1.5379x over previous
//
#include <hip/hip_runtime.h>
#include <math.h>

// clDice loss on 32x1x512x512: sigmoid + dice + 10x soft-skeletonize + skel dice.
// R1: removed contended double atomics -> per-block partials (1059 -> 466 us).
// R3: fused 2 skeletonize iters/kernel via two-stage LDS; traffic halved but
//     latency-bound: 128 thr x 44KB LDS = 6 waves/CU, VALUBusy 30%, occ 15% (485 us).
// R4: 256 thr/block (12 waves/CU), stage1 = 252 items (14 strips x 5 rows x 18 quads),
//     stage2 = 256 items (4-row strips), APITCH 80->84 to break strip bank aliasing.
// R5: resubmit of R4 — previous bench died to container infra flake, never measured.

#define H 512
#define W 512
#define IMG (H * W)
#define NIMG 64
#define NPRED 32

#define APITCH 84   // 21 quads: c=0 pad, c=1..18 data (gx = tileX + 4c - 8), c=19,20 pad
#define AROWS 74    // row r <-> gy = tileY + r - 4; data gy -4..67 (r 0..71), r 72,73 pad
#define BPITCH 72   // 18 quads, quad q <-> gx = tileX - 4 + 4q
#define BROWS 68    // row br <-> gy = tileY + br - 2

__device__ __forceinline__ float wsum64(float v) {
#pragma unroll
    for (int o = 32; o > 0; o >>= 1) v += __shfl_down(v, o);
    return v;
}

// hmin (3-wide row min) for 6 positions; h[j] <-> col base-1+j, via 3 aligned b128 reads.
__device__ __forceinline__ void hmin3(const float* __restrict__ row, float h[6]) {
    float4 q0 = *(const float4*)(row);
    float4 q1 = *(const float4*)(row + 4);
    float4 q2 = *(const float4*)(row + 8);
    h[0] = fminf(q0.z, fminf(q0.w, q1.x));
    h[1] = fminf(q0.w, fminf(q1.x, q1.y));
    h[2] = fminf(q1.x, fminf(q1.y, q1.z));
    h[3] = fminf(q1.y, fminf(q1.z, q1.w));
    h[4] = fminf(q1.z, fminf(q1.w, q2.x));
    h[5] = fminf(q1.w, fminf(q2.x, q2.y));
}

__device__ __forceinline__ void erode1(const float a[6], const float b[6], const float c[6],
                                       bool rowok, const bool cm[6], float e[6]) {
#pragma unroll
    for (int j = 0; j < 6; j++) {
        float v = fminf(a[j], fminf(b[j], c[j]));
        e[j] = (rowok && cm[j]) ? v : -INFINITY;
    }
}

__device__ __forceinline__ void erode2(const float a[6], const float b[6], const float c[6],
                                       int gy, bool lo, bool ro, float e[6]) {
    bool oob = (gy < 0) || (gy >= H);
#pragma unroll
    for (int j = 0; j < 6; j++) {
        float v = fminf(a[j], fminf(b[j], c[j]));
        e[j] = oob ? -INFINITY : v;
    }
    if (lo) e[0] = -INFINITY;
    if (ro) e[5] = -INFINITY;
}

__device__ __forceinline__ void hmax1(const float e[6], float hx[4], float ec[4]) {
    hx[0] = fmaxf(e[0], fmaxf(e[1], e[2]));
    hx[1] = fmaxf(e[1], fmaxf(e[2], e[3]));
    hx[2] = fmaxf(e[2], fmaxf(e[3], e[4]));
    hx[3] = fmaxf(e[3], fmaxf(e[4], e[5]));
    ec[0] = e[1]; ec[1] = e[2]; ec[2] = e[3]; ec[3] = e[4];
}

// Fill LDS A from src; non-data region and out-of-image = +inf (erosion-neutral).
template<int SIG>
__device__ void fillA(float* __restrict__ A, const float* __restrict__ src,
                      int tileX, int tileY, int tid) {
    const float PINF = INFINITY;
    for (int it = tid; it < AROWS * 21; it += 256) {
        int r = it / 21;
        int c = it - r * 21;
        int gy = tileY + r - 4;
        int gx = tileX + 4 * c - 8;
        float4 v = make_float4(PINF, PINF, PINF, PINF);
        if ((unsigned)(c - 1) < 18u && (unsigned)gy < (unsigned)H &&
            (unsigned)gx < (unsigned)W) {
            v = *(const float4*)(src + (size_t)gy * W + gx);
            if (SIG) {
                v.x = 1.0f / (1.0f + __expf(-v.x));
                v.y = 1.0f / (1.0f + __expf(-v.y));
                v.z = 1.0f / (1.0f + __expf(-v.z));
                v.w = 1.0f / (1.0f + __expf(-v.w));
            }
        }
        *(float4*)(A + r * APITCH + 4 * c) = v;
    }
}

// Stage 1: one skeletonize iteration A -> B. 252 items = 14 strips(5 rows) x 18 quads.
// Strip s outputs rows br = 5s..5s+4 (gy = tileY-2+5s ..); br >= 68 skipped.
__device__ void stage1(const float* __restrict__ A, float* __restrict__ B,
                       int tileX, int tileY, int tid) {
    for (int item = tid; item < 252; item += 256) {
        const int s = item / 18;
        const int q = item - s * 18;
        const int gcb = tileX - 4 + 4 * q;       // output quad base col (global)
        const int ys = tileY - 2 + 5 * s;        // first output row (global)
        bool cm[6], sm[4];
#pragma unroll
        for (int j = 0; j < 6; j++) cm[j] = ((unsigned)(gcb - 1 + j) < (unsigned)W);
#pragma unroll
        for (int j = 0; j < 4; j++) sm[j] = ((unsigned)(gcb + j) < (unsigned)W);
        const int lr = 5 * s + 2;                // A-local row of ys
        const float* Ab = A + 4 * q;
        float hm[3][6], hx[3][4], e[6], ec_cur[4], ec_nxt[4];
        hmin3(Ab + (lr - 2) * APITCH, hm[0]);
        hmin3(Ab + (lr - 1) * APITCH, hm[1]);
        hmin3(Ab + (lr + 0) * APITCH, hm[2]);
        erode1(hm[0], hm[1], hm[2], (unsigned)(ys - 1) < (unsigned)H, cm, e);
        hmax1(e, hx[0], ec_nxt);
        hmin3(Ab + (lr + 1) * APITCH, hm[0]);
        erode1(hm[1], hm[2], hm[0], (unsigned)ys < (unsigned)H, cm, e);
        hmax1(e, hx[1], ec_cur);
#pragma unroll
        for (int k = 0; k < 5; k++) {
            hmin3(Ab + (lr + 2 + k) * APITCH, hm[(k + 1) % 3]);
            erode1(hm[(k + 2) % 3], hm[k % 3], hm[(k + 1) % 3],
                   (unsigned)(ys + k + 1) < (unsigned)H, cm, e);
            hmax1(e, hx[(k + 2) % 3], ec_nxt);
            float t0 = fmaxf(hx[k % 3][0], fmaxf(hx[(k + 1) % 3][0], hx[(k + 2) % 3][0]));
            float t1 = fmaxf(hx[k % 3][1], fmaxf(hx[(k + 1) % 3][1], hx[(k + 2) % 3][1]));
            float t2 = fmaxf(hx[k % 3][2], fmaxf(hx[(k + 1) % 3][2], hx[(k + 2) % 3][2]));
            float t3 = fmaxf(hx[k % 3][3], fmaxf(hx[(k + 1) % 3][3], hx[(k + 2) % 3][3]));
            float4 sc = *(const float4*)(A + (lr + k) * APITCH + 4 * q + 4);
            float o0 = fminf(fmaxf(sc.x - (sc.x - ec_cur[0]) * t0, 0.0f), 1.0f);
            float o1 = fminf(fmaxf(sc.y - (sc.y - ec_cur[1]) * t1, 0.0f), 1.0f);
            float o2 = fminf(fmaxf(sc.z - (sc.z - ec_cur[2]) * t2, 0.0f), 1.0f);
            float o3 = fminf(fmaxf(sc.w - (sc.w - ec_cur[3]) * t3, 0.0f), 1.0f);
            int br = 5 * s + k;
            if (br < BROWS) {
                bool rin = ((unsigned)(ys + k) < (unsigned)H);
                float4 ov;
                ov.x = (rin && sm[0]) ? o0 : INFINITY;
                ov.y = (rin && sm[1]) ? o1 : INFINITY;
                ov.z = (rin && sm[2]) ? o2 : INFINITY;
                ov.w = (rin && sm[3]) ? o3 : INFINITY;
                *(float4*)(B + br * BPITCH + 4 * q) = ov;
            }
            ec_cur[0] = ec_nxt[0]; ec_cur[1] = ec_nxt[1];
            ec_cur[2] = ec_nxt[2]; ec_cur[3] = ec_nxt[3];
        }
    }
}

// Stage 2: second iteration B -> interior 64x64. 256 threads: 16 col-quads x 16
// 4-row strips; output to global or to registers.
template<bool TOREG>
__device__ void stage2(const float* __restrict__ B, int tileX, int tileY,
                       int tx, int ty, float* __restrict__ gdst, float (*oreg)[4]) {
    const int X = tileX + 4 * tx;
    const int gy0 = tileY + 4 * ty;
    const int rb = 4 * ty + 2;                   // B-local row of gy0
    const bool lo = (X == 0);
    const bool ro = (X + 4 >= W);
    const float* Bb = B + 4 * tx;
    float hm[3][6], hx[3][4], e[6], ec_cur[4], ec_nxt[4];
    hmin3(Bb + (rb - 2) * BPITCH, hm[0]);
    hmin3(Bb + (rb - 1) * BPITCH, hm[1]);
    hmin3(Bb + (rb + 0) * BPITCH, hm[2]);
    erode2(hm[0], hm[1], hm[2], gy0 - 1, lo, ro, e);
    hmax1(e, hx[0], ec_nxt);
    hmin3(Bb + (rb + 1) * BPITCH, hm[0]);
    erode2(hm[1], hm[2], hm[0], gy0, lo, ro, e);
    hmax1(e, hx[1], ec_cur);
#pragma unroll
    for (int k = 0; k < 4; k++) {
        hmin3(Bb + (rb + 2 + k) * BPITCH, hm[(k + 1) % 3]);
        erode2(hm[(k + 2) % 3], hm[k % 3], hm[(k + 1) % 3], gy0 + k + 1, lo, ro, e);
        hmax1(e, hx[(k + 2) % 3], ec_nxt);
        float t0 = fmaxf(hx[k % 3][0], fmaxf(hx[(k + 1) % 3][0], hx[(k + 2) % 3][0]));
        float t1 = fmaxf(hx[k % 3][1], fmaxf(hx[(k + 1) % 3][1], hx[(k + 2) % 3][1]));
        float t2 = fmaxf(hx[k % 3][2], fmaxf(hx[(k + 1) % 3][2], hx[(k + 2) % 3][2]));
        float t3 = fmaxf(hx[k % 3][3], fmaxf(hx[(k + 1) % 3][3], hx[(k + 2) % 3][3]));
        float4 sc = *(const float4*)(B + (rb + k) * BPITCH + 4 * tx + 4);
        float4 o;
        o.x = fminf(fmaxf(sc.x - (sc.x - ec_cur[0]) * t0, 0.0f), 1.0f);
        o.y = fminf(fmaxf(sc.y - (sc.y - ec_cur[1]) * t1, 0.0f), 1.0f);
        o.z = fminf(fmaxf(sc.z - (sc.z - ec_cur[2]) * t2, 0.0f), 1.0f);
        o.w = fminf(fmaxf(sc.w - (sc.w - ec_cur[3]) * t3, 0.0f), 1.0f);
        if (TOREG) {
            oreg[k][0] = o.x; oreg[k][1] = o.y; oreg[k][2] = o.z; oreg[k][3] = o.w;
        } else {
            *(float4*)(gdst + (size_t)(gy0 + k) * W + X) = o;
        }
        ec_cur[0] = ec_nxt[0]; ec_cur[1] = ec_nxt[1];
        ec_cur[2] = ec_nxt[2]; ec_cur[3] = ec_nxt[3];
    }
}

// ---- K1: sigmoid + dice partials + iters 1,2 ----
__global__ __launch_bounds__(256, 3) void k_first(
    const float* __restrict__ logits, const float* __restrict__ target,
    float* __restrict__ outb, float* __restrict__ parts0, float* __restrict__ parts1) {
    __shared__ float A[AROWS * APITCH];
    __shared__ float B[BROWS * BPITCH];
    __shared__ float red[8];
    const int img = blockIdx.z;
    const int tileX = blockIdx.x * 64, tileY = blockIdx.y * 64;
    const int tid = threadIdx.y * 16 + threadIdx.x;
    const bool pred = (img < NPRED);
    if (pred) fillA<1>(A, logits + (size_t)img * IMG, tileX, tileY, tid);
    else      fillA<0>(A, target + (size_t)(img - NPRED) * IMG, tileX, tileY, tid);
    __syncthreads();
    float a = 0.0f, b = 0.0f;
    if (pred) {
        const float* tgt = target + (size_t)img * IMG;
        for (int i = tid; i < 1024; i += 256) {
            int r = i >> 4, c4 = (i & 15) * 4;
            float4 p = *(const float4*)(A + (r + 4) * APITCH + c4 + 8);
            float4 t = *(const float4*)(tgt + (size_t)(tileY + r) * W + tileX + c4);
            a += p.x * t.x + p.y * t.y + p.z * t.z + p.w * t.w;
            b += p.x + p.y + p.z + p.w;
        }
    } else {
        for (int i = tid; i < 1024; i += 256) {
            int r = i >> 4, c4 = (i & 15) * 4;
            float4 t = *(const float4*)(A + (r + 4) * APITCH + c4 + 8);
            a += t.x + t.y + t.z + t.w;
        }
    }
    a = wsum64(a); b = wsum64(b);
    if ((tid & 63) == 0) { red[tid >> 6] = a; red[4 + (tid >> 6)] = b; }
    stage1(A, B, tileX, tileY, tid);
    __syncthreads();
    if (tid == 0) {
        int bi = blockIdx.z * 64 + blockIdx.y * 8 + blockIdx.x;
        parts0[bi] = red[0] + red[1] + red[2] + red[3];
        parts1[bi] = red[4] + red[5] + red[6] + red[7];
    }
    stage2<false>(B, tileX, tileY, threadIdx.x, threadIdx.y,
                  outb + (size_t)img * IMG, nullptr);
}

// ---- K2..K4: two iterations, buf -> buf ----
__global__ __launch_bounds__(256, 3) void k_mid(
    const float* __restrict__ in, float* __restrict__ outb) {
    __shared__ float A[AROWS * APITCH];
    __shared__ float B[BROWS * BPITCH];
    const int img = blockIdx.z;
    const int tileX = blockIdx.x * 64, tileY = blockIdx.y * 64;
    const int tid = threadIdx.y * 16 + threadIdx.x;
    fillA<0>(A, in + (size_t)img * IMG, tileX, tileY, tid);
    __syncthreads();
    stage1(A, B, tileX, tileY, tid);
    __syncthreads();
    stage2<false>(B, tileX, tileY, threadIdx.x, threadIdx.y,
                  outb + (size_t)img * IMG, nullptr);
}

// ---- K5: iters 9,10 for pred tile AND matching target tile; skel-dice partials ----
__global__ __launch_bounds__(256, 3) void k_last(
    const float* __restrict__ in, float* __restrict__ pA,
    float* __restrict__ pB, float* __restrict__ pC) {
    __shared__ float A[AROWS * APITCH];
    __shared__ float B[BROWS * BPITCH];
    __shared__ float red[12];
    const int img = blockIdx.z;                  // 0..31
    const int tileX = blockIdx.x * 64, tileY = blockIdx.y * 64;
    const int tid = threadIdx.y * 16 + threadIdx.x;
    float op[4][4], ot[4][4];
    fillA<0>(A, in + (size_t)img * IMG, tileX, tileY, tid);
    __syncthreads();
    stage1(A, B, tileX, tileY, tid);
    __syncthreads();
    stage2<true>(B, tileX, tileY, threadIdx.x, threadIdx.y, nullptr, op);
    fillA<0>(A, in + (size_t)(img + NPRED) * IMG, tileX, tileY, tid);
    __syncthreads();   // all threads past stage2 B-reads before stage1 rewrites B
    stage1(A, B, tileX, tileY, tid);
    __syncthreads();
    stage2<true>(B, tileX, tileY, threadIdx.x, threadIdx.y, nullptr, ot);
    float a = 0.0f, b = 0.0f, c = 0.0f;
#pragma unroll
    for (int k = 0; k < 4; k++)
#pragma unroll
        for (int j = 0; j < 4; j++) {
            a += op[k][j] * ot[k][j];
            b += op[k][j];
            c += ot[k][j];
        }
    a = wsum64(a); b = wsum64(b); c = wsum64(c);
    if ((tid & 63) == 0) {
        red[tid >> 6] = a; red[4 + (tid >> 6)] = b; red[8 + (tid >> 6)] = c;
    }
    __syncthreads();
    if (tid == 0) {
        int bi = img * 64 + blockIdx.y * 8 + blockIdx.x;
        pA[bi] = red[0] + red[1] + red[2] + red[3];
        pB[bi] = red[4] + red[5] + red[6] + red[7];
        pC[bi] = red[8] + red[9] + red[10] + red[11];
    }
}

// ---- per-image dice from 64 tile partials (1 wave per image) ----
__global__ __launch_bounds__(64) void finalize_img(
    const float* __restrict__ parts0, const float* __restrict__ parts1,
    const float* __restrict__ pA, const float* __restrict__ pB,
    const float* __restrict__ pC, float* __restrict__ dices) {
    const int i = blockIdx.x, t = threadIdx.x;
    float inter = wsum64(parts0[i * 64 + t]);
    float sp = wsum64(parts1[i * 64 + t]);
    float st = wsum64(parts0[(NPRED + i) * 64 + t]);
    float i2 = wsum64(pA[i * 64 + t]);
    float sp2 = wsum64(pB[i * 64 + t]);
    float st2 = wsum64(pC[i * 64 + t]);
    if (t == 0) {
        dices[i] = (float)((2.0 * (double)inter + 1e-5) / ((double)sp + (double)st + 1e-5));
        dices[32 + i] = (float)((2.0 * (double)i2 + 1e-5) / ((double)sp2 + (double)st2 + 1e-5));
    }
}

__global__ void finalize_out(const float* __restrict__ dices, float* __restrict__ out) {
    const int t = threadIdx.x;
    double d = 0.0, sd = 0.0;
    if (t < 32) { d = dices[t]; sd = dices[32 + t]; }
#pragma unroll
    for (int o = 32; o > 0; o >>= 1) { d += __shfl_down(d, o); sd += __shfl_down(sd, o); }
    if (t == 0) {
        d *= (1.0 / 32.0); sd *= (1.0 / 32.0);
        out[0] = (float)(0.5 * (1.0 - d) + 0.5 * (1.0 - sd));
        out[1] = (float)d;
        out[2] = (float)sd;
    }
}

extern "C" void kernel_launch(void* const* d_in, const int* in_sizes, int n_in,
                              void* d_out, int out_size, void* d_ws, size_t ws_size,
                              hipStream_t stream) {
    (void)in_sizes; (void)n_in; (void)out_size; (void)ws_size;
    const float* logits = (const float*)d_in[0];
    const float* target = (const float*)d_in[1];
    float* out = (float*)d_out;
    float* buf0 = (float*)d_ws;
    float* buf1 = buf0 + (size_t)NIMG * IMG;
    float* parts0 = buf1 + (size_t)NIMG * IMG;   // 4096
    float* parts1 = parts0 + 4096;               // 4096
    float* pA = parts1 + 4096;                   // 2048
    float* pB = pA + 2048;
    float* pC = pB + 2048;
    float* dices = pC + 2048;                    // 64

    dim3 blk(16, 16, 1);
    k_first<<<dim3(8, 8, NIMG), blk, 0, stream>>>(logits, target, buf0, parts0, parts1);
    k_mid<<<dim3(8, 8, NIMG), blk, 0, stream>>>(buf0, buf1);   // iters 3,4
    k_mid<<<dim3(8, 8, NIMG), blk, 0, stream>>>(buf1, buf0);   // iters 5,6
    k_mid<<<dim3(8, 8, NIMG), blk, 0, stream>>>(buf0, buf1);   // iters 7,8
    k_last<<<dim3(8, 8, NPRED), blk, 0, stream>>>(buf1, pA, pB, pC);  // iters 9,10 + partials
    finalize_img<<<32, 64, 0, stream>>>(parts0, parts1, pA, pB, pC, dices);
    finalize_out<<<1, 64, 0, stream>>>(dices, out);
}

// Round 6
// 312.691 us; speedup vs baseline: 1.5526x; 1.0095x over previous
//
#include <hip/hip_runtime.h>
#include <math.h>

// clDice loss on 32x1x512x512: sigmoid + dice + 10x soft-skeletonize + skel dice.
// R1: removed contended double atomics -> per-block partials (1059 -> 466 us).
// R3: fused 2 skeletonize iters/kernel via two-stage LDS (485 us, latency-bound).
// R5: 256 thr/block, 12 waves/CU (316 us; VALUBusy 46%, conflicts 6.9M unchanged
//     by A-pitch change -> conflicts are B-access: 4-row strip stride 72*4*4B == 0
//     mod 128 puts all 4 ty-groups of a wave on one bank phase).
// R6: BPITCH 72->76 (strip stride 16 mod 32: 8-way -> 4-way) + center-quad register
//     rolling in both stages (ds_read_b128 per quad-row 4 -> 3).

#define H 512
#define W 512
#define IMG (H * W)
#define NIMG 64
#define NPRED 32

#define APITCH 84   // 21 quads: c=0 pad, c=1..18 data (gx = tileX + 4c - 8), c=19,20 pad
#define AROWS 74    // row r <-> gy = tileY + r - 4; data gy -4..67 (r 0..71), r 72,73 pad
#define BPITCH 76   // 18 data quads + 1 pad quad; quad q <-> gx = tileX - 4 + 4q
#define BROWS 68    // row br <-> gy = tileY + br - 2

__device__ __forceinline__ float wsum64(float v) {
#pragma unroll
    for (int o = 32; o > 0; o >>= 1) v += __shfl_down(v, o);
    return v;
}

// hmin (3-wide row min) for 6 positions; h[j] <-> col base-1+j, via 3 aligned b128
// reads. Also returns the center quad q1 (cols base..base+3) for register reuse.
__device__ __forceinline__ void hmin3(const float* __restrict__ row, float h[6],
                                      float4& q1out) {
    float4 q0 = *(const float4*)(row);
    float4 q1 = *(const float4*)(row + 4);
    float4 q2 = *(const float4*)(row + 8);
    q1out = q1;
    h[0] = fminf(q0.z, fminf(q0.w, q1.x));
    h[1] = fminf(q0.w, fminf(q1.x, q1.y));
    h[2] = fminf(q1.x, fminf(q1.y, q1.z));
    h[3] = fminf(q1.y, fminf(q1.z, q1.w));
    h[4] = fminf(q1.z, fminf(q1.w, q2.x));
    h[5] = fminf(q1.w, fminf(q2.x, q2.y));
}

__device__ __forceinline__ void erode1(const float a[6], const float b[6], const float c[6],
                                       bool rowok, const bool cm[6], float e[6]) {
#pragma unroll
    for (int j = 0; j < 6; j++) {
        float v = fminf(a[j], fminf(b[j], c[j]));
        e[j] = (rowok && cm[j]) ? v : -INFINITY;
    }
}

__device__ __forceinline__ void erode2(const float a[6], const float b[6], const float c[6],
                                       int gy, bool lo, bool ro, float e[6]) {
    bool oob = (gy < 0) || (gy >= H);
#pragma unroll
    for (int j = 0; j < 6; j++) {
        float v = fminf(a[j], fminf(b[j], c[j]));
        e[j] = oob ? -INFINITY : v;
    }
    if (lo) e[0] = -INFINITY;
    if (ro) e[5] = -INFINITY;
}

__device__ __forceinline__ void hmax1(const float e[6], float hx[4], float ec[4]) {
    hx[0] = fmaxf(e[0], fmaxf(e[1], e[2]));
    hx[1] = fmaxf(e[1], fmaxf(e[2], e[3]));
    hx[2] = fmaxf(e[2], fmaxf(e[3], e[4]));
    hx[3] = fmaxf(e[3], fmaxf(e[4], e[5]));
    ec[0] = e[1]; ec[1] = e[2]; ec[2] = e[3]; ec[3] = e[4];
}

// Fill LDS A from src; non-data region and out-of-image = +inf (erosion-neutral).
template<int SIG>
__device__ void fillA(float* __restrict__ A, const float* __restrict__ src,
                      int tileX, int tileY, int tid) {
    const float PINF = INFINITY;
    for (int it = tid; it < AROWS * 21; it += 256) {
        int r = it / 21;
        int c = it - r * 21;
        int gy = tileY + r - 4;
        int gx = tileX + 4 * c - 8;
        float4 v = make_float4(PINF, PINF, PINF, PINF);
        if ((unsigned)(c - 1) < 18u && (unsigned)gy < (unsigned)H &&
            (unsigned)gx < (unsigned)W) {
            v = *(const float4*)(src + (size_t)gy * W + gx);
            if (SIG) {
                v.x = 1.0f / (1.0f + __expf(-v.x));
                v.y = 1.0f / (1.0f + __expf(-v.y));
                v.z = 1.0f / (1.0f + __expf(-v.z));
                v.w = 1.0f / (1.0f + __expf(-v.w));
            }
        }
        *(float4*)(A + r * APITCH + 4 * c) = v;
    }
}

// Stage 1: one skeletonize iteration A -> B. 252 items = 14 strips(5 rows) x 18 quads.
// Strip s outputs rows br = 5s..5s+4 (gy = tileY-2+5s ..); br >= 68 skipped.
__device__ void stage1(const float* __restrict__ A, float* __restrict__ B,
                       int tileX, int tileY, int tid) {
    for (int item = tid; item < 252; item += 256) {
        const int s = item / 18;
        const int q = item - s * 18;
        const int gcb = tileX - 4 + 4 * q;       // output quad base col (global)
        const int ys = tileY - 2 + 5 * s;        // first output row (global)
        bool cm[6], sm[4];
#pragma unroll
        for (int j = 0; j < 6; j++) cm[j] = ((unsigned)(gcb - 1 + j) < (unsigned)W);
#pragma unroll
        for (int j = 0; j < 4; j++) sm[j] = ((unsigned)(gcb + j) < (unsigned)W);
        const int lr = 5 * s + 2;                // A-local row of ys
        const float* Ab = A + 4 * q;
        float hm[3][6], hx[3][4], e[6], ec_cur[4], ec_nxt[4];
        float4 scq[3], qd;
        hmin3(Ab + (lr - 2) * APITCH, hm[0], qd);
        hmin3(Ab + (lr - 1) * APITCH, hm[1], qd);
        hmin3(Ab + (lr + 0) * APITCH, hm[2], scq[0]);   // center of output row 0
        erode1(hm[0], hm[1], hm[2], (unsigned)(ys - 1) < (unsigned)H, cm, e);
        hmax1(e, hx[0], ec_nxt);
        hmin3(Ab + (lr + 1) * APITCH, hm[0], scq[1]);   // center of output row 1
        erode1(hm[1], hm[2], hm[0], (unsigned)ys < (unsigned)H, cm, e);
        hmax1(e, hx[1], ec_cur);
#pragma unroll
        for (int k = 0; k < 5; k++) {
            hmin3(Ab + (lr + 2 + k) * APITCH, hm[(k + 1) % 3], scq[(2 + k) % 3]);
            erode1(hm[(k + 2) % 3], hm[k % 3], hm[(k + 1) % 3],
                   (unsigned)(ys + k + 1) < (unsigned)H, cm, e);
            hmax1(e, hx[(k + 2) % 3], ec_nxt);
            float t0 = fmaxf(hx[k % 3][0], fmaxf(hx[(k + 1) % 3][0], hx[(k + 2) % 3][0]));
            float t1 = fmaxf(hx[k % 3][1], fmaxf(hx[(k + 1) % 3][1], hx[(k + 2) % 3][1]));
            float t2 = fmaxf(hx[k % 3][2], fmaxf(hx[(k + 1) % 3][2], hx[(k + 2) % 3][2]));
            float t3 = fmaxf(hx[k % 3][3], fmaxf(hx[(k + 1) % 3][3], hx[(k + 2) % 3][3]));
            float4 sc = scq[k % 3];              // center row from register history
            float o0 = fminf(fmaxf(sc.x - (sc.x - ec_cur[0]) * t0, 0.0f), 1.0f);
            float o1 = fminf(fmaxf(sc.y - (sc.y - ec_cur[1]) * t1, 0.0f), 1.0f);
            float o2 = fminf(fmaxf(sc.z - (sc.z - ec_cur[2]) * t2, 0.0f), 1.0f);
            float o3 = fminf(fmaxf(sc.w - (sc.w - ec_cur[3]) * t3, 0.0f), 1.0f);
            int br = 5 * s + k;
            if (br < BROWS) {
                bool rin = ((unsigned)(ys + k) < (unsigned)H);
                float4 ov;
                ov.x = (rin && sm[0]) ? o0 : INFINITY;
                ov.y = (rin && sm[1]) ? o1 : INFINITY;
                ov.z = (rin && sm[2]) ? o2 : INFINITY;
                ov.w = (rin && sm[3]) ? o3 : INFINITY;
                *(float4*)(B + br * BPITCH + 4 * q) = ov;
            }
            ec_cur[0] = ec_nxt[0]; ec_cur[1] = ec_nxt[1];
            ec_cur[2] = ec_nxt[2]; ec_cur[3] = ec_nxt[3];
        }
    }
}

// Stage 2: second iteration B -> interior 64x64. 256 threads: 16 col-quads x 16
// 4-row strips; output to global or to registers.
template<bool TOREG>
__device__ void stage2(const float* __restrict__ B, int tileX, int tileY,
                       int tx, int ty, float* __restrict__ gdst, float (*oreg)[4]) {
    const int X = tileX + 4 * tx;
    const int gy0 = tileY + 4 * ty;
    const int rb = 4 * ty + 2;                   // B-local row of gy0
    const bool lo = (X == 0);
    const bool ro = (X + 4 >= W);
    const float* Bb = B + 4 * tx;
    float hm[3][6], hx[3][4], e[6], ec_cur[4], ec_nxt[4];
    float4 scq[3], qd;
    hmin3(Bb + (rb - 2) * BPITCH, hm[0], qd);
    hmin3(Bb + (rb - 1) * BPITCH, hm[1], qd);
    hmin3(Bb + (rb + 0) * BPITCH, hm[2], scq[0]);
    erode2(hm[0], hm[1], hm[2], gy0 - 1, lo, ro, e);
    hmax1(e, hx[0], ec_nxt);
    hmin3(Bb + (rb + 1) * BPITCH, hm[0], scq[1]);
    erode2(hm[1], hm[2], hm[0], gy0, lo, ro, e);
    hmax1(e, hx[1], ec_cur);
#pragma unroll
    for (int k = 0; k < 4; k++) {
        hmin3(Bb + (rb + 2 + k) * BPITCH, hm[(k + 1) % 3], scq[(2 + k) % 3]);
        erode2(hm[(k + 2) % 3], hm[k % 3], hm[(k + 1) % 3], gy0 + k + 1, lo, ro, e);
        hmax1(e, hx[(k + 2) % 3], ec_nxt);
        float t0 = fmaxf(hx[k % 3][0], fmaxf(hx[(k + 1) % 3][0], hx[(k + 2) % 3][0]));
        float t1 = fmaxf(hx[k % 3][1], fmaxf(hx[(k + 1) % 3][1], hx[(k + 2) % 3][1]));
        float t2 = fmaxf(hx[k % 3][2], fmaxf(hx[(k + 1) % 3][2], hx[(k + 2) % 3][2]));
        float t3 = fmaxf(hx[k % 3][3], fmaxf(hx[(k + 1) % 3][3], hx[(k + 2) % 3][3]));
        float4 sc = scq[k % 3];
        float4 o;
        o.x = fminf(fmaxf(sc.x - (sc.x - ec_cur[0]) * t0, 0.0f), 1.0f);
        o.y = fminf(fmaxf(sc.y - (sc.y - ec_cur[1]) * t1, 0.0f), 1.0f);
        o.z = fminf(fmaxf(sc.z - (sc.z - ec_cur[2]) * t2, 0.0f), 1.0f);
        o.w = fminf(fmaxf(sc.w - (sc.w - ec_cur[3]) * t3, 0.0f), 1.0f);
        if (TOREG) {
            oreg[k][0] = o.x; oreg[k][1] = o.y; oreg[k][2] = o.z; oreg[k][3] = o.w;
        } else {
            *(float4*)(gdst + (size_t)(gy0 + k) * W + X) = o;
        }
        ec_cur[0] = ec_nxt[0]; ec_cur[1] = ec_nxt[1];
        ec_cur[2] = ec_nxt[2]; ec_cur[3] = ec_nxt[3];
    }
}

// ---- K1: sigmoid + dice partials + iters 1,2 ----
__global__ __launch_bounds__(256, 3) void k_first(
    const float* __restrict__ logits, const float* __restrict__ target,
    float* __restrict__ outb, float* __restrict__ parts0, float* __restrict__ parts1) {
    __shared__ float A[AROWS * APITCH];
    __shared__ float B[BROWS * BPITCH];
    __shared__ float red[8];
    const int img = blockIdx.z;
    const int tileX = blockIdx.x * 64, tileY = blockIdx.y * 64;
    const int tid = threadIdx.y * 16 + threadIdx.x;
    const bool pred = (img < NPRED);
    if (pred) fillA<1>(A, logits + (size_t)img * IMG, tileX, tileY, tid);
    else      fillA<0>(A, target + (size_t)(img - NPRED) * IMG, tileX, tileY, tid);
    __syncthreads();
    float a = 0.0f, b = 0.0f;
    if (pred) {
        const float* tgt = target + (size_t)img * IMG;
        for (int i = tid; i < 1024; i += 256) {
            int r = i >> 4, c4 = (i & 15) * 4;
            float4 p = *(const float4*)(A + (r + 4) * APITCH + c4 + 8);
            float4 t = *(const float4*)(tgt + (size_t)(tileY + r) * W + tileX + c4);
            a += p.x * t.x + p.y * t.y + p.z * t.z + p.w * t.w;
            b += p.x + p.y + p.z + p.w;
        }
    } else {
        for (int i = tid; i < 1024; i += 256) {
            int r = i >> 4, c4 = (i & 15) * 4;
            float4 t = *(const float4*)(A + (r + 4) * APITCH + c4 + 8);
            a += t.x + t.y + t.z + t.w;
        }
    }
    a = wsum64(a); b = wsum64(b);
    if ((tid & 63) == 0) { red[tid >> 6] = a; red[4 + (tid >> 6)] = b; }
    stage1(A, B, tileX, tileY, tid);
    __syncthreads();
    if (tid == 0) {
        int bi = blockIdx.z * 64 + blockIdx.y * 8 + blockIdx.x;
        parts0[bi] = red[0] + red[1] + red[2] + red[3];
        parts1[bi] = red[4] + red[5] + red[6] + red[7];
    }
    stage2<false>(B, tileX, tileY, threadIdx.x, threadIdx.y,
                  outb + (size_t)img * IMG, nullptr);
}

// ---- K2..K4: two iterations, buf -> buf ----
__global__ __launch_bounds__(256, 3) void k_mid(
    const float* __restrict__ in, float* __restrict__ outb) {
    __shared__ float A[AROWS * APITCH];
    __shared__ float B[BROWS * BPITCH];
    const int img = blockIdx.z;
    const int tileX = blockIdx.x * 64, tileY = blockIdx.y * 64;
    const int tid = threadIdx.y * 16 + threadIdx.x;
    fillA<0>(A, in + (size_t)img * IMG, tileX, tileY, tid);
    __syncthreads();
    stage1(A, B, tileX, tileY, tid);
    __syncthreads();
    stage2<false>(B, tileX, tileY, threadIdx.x, threadIdx.y,
                  outb + (size_t)img * IMG, nullptr);
}

// ---- K5: iters 9,10 for pred tile AND matching target tile; skel-dice partials ----
__global__ __launch_bounds__(256, 3) void k_last(
    const float* __restrict__ in, float* __restrict__ pA,
    float* __restrict__ pB, float* __restrict__ pC) {
    __shared__ float A[AROWS * APITCH];
    __shared__ float B[BROWS * BPITCH];
    __shared__ float red[12];
    const int img = blockIdx.z;                  // 0..31
    const int tileX = blockIdx.x * 64, tileY = blockIdx.y * 64;
    const int tid = threadIdx.y * 16 + threadIdx.x;
    float op[4][4], ot[4][4];
    fillA<0>(A, in + (size_t)img * IMG, tileX, tileY, tid);
    __syncthreads();
    stage1(A, B, tileX, tileY, tid);
    __syncthreads();
    stage2<true>(B, tileX, tileY, threadIdx.x, threadIdx.y, nullptr, op);
    fillA<0>(A, in + (size_t)(img + NPRED) * IMG, tileX, tileY, tid);
    __syncthreads();   // all threads past stage2 B-reads before stage1 rewrites B
    stage1(A, B, tileX, tileY, tid);
    __syncthreads();
    stage2<true>(B, tileX, tileY, threadIdx.x, threadIdx.y, nullptr, ot);
    float a = 0.0f, b = 0.0f, c = 0.0f;
#pragma unroll
    for (int k = 0; k < 4; k++)
#pragma unroll
        for (int j = 0; j < 4; j++) {
            a += op[k][j] * ot[k][j];
            b += op[k][j];
            c += ot[k][j];
        }
    a = wsum64(a); b = wsum64(b); c = wsum64(c);
    if ((tid & 63) == 0) {
        red[tid >> 6] = a; red[4 + (tid >> 6)] = b; red[8 + (tid >> 6)] = c;
    }
    __syncthreads();
    if (tid == 0) {
        int bi = img * 64 + blockIdx.y * 8 + blockIdx.x;
        pA[bi] = red[0] + red[1] + red[2] + red[3];
        pB[bi] = red[4] + red[5] + red[6] + red[7];
        pC[bi] = red[8] + red[9] + red[10] + red[11];
    }
}

// ---- per-image dice from 64 tile partials (1 wave per image) ----
__global__ __launch_bounds__(64) void finalize_img(
    const float* __restrict__ parts0, const float* __restrict__ parts1,
    const float* __restrict__ pA, const float* __restrict__ pB,
    const float* __restrict__ pC, float* __restrict__ dices) {
    const int i = blockIdx.x, t = threadIdx.x;
    float inter = wsum64(parts0[i * 64 + t]);
    float sp = wsum64(parts1[i * 64 + t]);
    float st = wsum64(parts0[(NPRED + i) * 64 + t]);
    float i2 = wsum64(pA[i * 64 + t]);
    float sp2 = wsum64(pB[i * 64 + t]);
    float st2 = wsum64(pC[i * 64 + t]);
    if (t == 0) {
        dices[i] = (float)((2.0 * (double)inter + 1e-5) / ((double)sp + (double)st + 1e-5));
        dices[32 + i] = (float)((2.0 * (double)i2 + 1e-5) / ((double)sp2 + (double)st2 + 1e-5));
    }
}

__global__ void finalize_out(const float* __restrict__ dices, float* __restrict__ out) {
    const int t = threadIdx.x;
    double d = 0.0, sd = 0.0;
    if (t < 32) { d = dices[t]; sd = dices[32 + t]; }
#pragma unroll
    for (int o = 32; o > 0; o >>= 1) { d += __shfl_down(d, o); sd += __shfl_down(sd, o); }
    if (t == 0) {
        d *= (1.0 / 32.0); sd *= (1.0 / 32.0);
        out[0] = (float)(0.5 * (1.0 - d) + 0.5 * (1.0 - sd));
        out[1] = (float)d;
        out[2] = (float)sd;
    }
}

extern "C" void kernel_launch(void* const* d_in, const int* in_sizes, int n_in,
                              void* d_out, int out_size, void* d_ws, size_t ws_size,
                              hipStream_t stream) {
    (void)in_sizes; (void)n_in; (void)out_size; (void)ws_size;
    const float* logits = (const float*)d_in[0];
    const float* target = (const float*)d_in[1];
    float* out = (float*)d_out;
    float* buf0 = (float*)d_ws;
    float* buf1 = buf0 + (size_t)NIMG * IMG;
    float* parts0 = buf1 + (size_t)NIMG * IMG;   // 4096
    float* parts1 = parts0 + 4096;               // 4096
    float* pA = parts1 + 4096;                   // 2048
    float* pB = pA + 2048;
    float* pC = pB + 2048;
    float* dices = pC + 2048;                    // 64

    dim3 blk(16, 16, 1);
    k_first<<<dim3(8, 8, NIMG), blk, 0, stream>>>(logits, target, buf0, parts0, parts1);
    k_mid<<<dim3(8, 8, NIMG), blk, 0, stream>>>(buf0, buf1);   // iters 3,4
    k_mid<<<dim3(8, 8, NIMG), blk, 0, stream>>>(buf1, buf0);   // iters 5,6
    k_mid<<<dim3(8, 8, NIMG), blk, 0, stream>>>(buf0, buf1);   // iters 7,8
    k_last<<<dim3(8, 8, NPRED), blk, 0, stream>>>(buf1, pA, pB, pC);  // iters 9,10 + partials
    finalize_img<<<32, 64, 0, stream>>>(parts0, parts1, pA, pB, pC, dices);
    finalize_out<<<1, 64, 0, stream>>>(dices, out);
}

// Round 8
// 261.935 us; speedup vs baseline: 1.8534x; 1.1938x over previous
//
#include <hip/hip_runtime.h>
#include <hip/hip_fp16.h>
#include <math.h>

// clDice loss on 32x1x512x512: sigmoid + dice + 10x soft-skeletonize + skel dice.
// R1: removed contended double atomics -> per-block partials (1059 -> 466 us).
// R3: fused 2 skeletonize iters/kernel via two-stage LDS (485 us, latency-bound).
// R5: 256 thr/block, 12 waves/CU (316 us).
// R6: B-pitch + center-quad register rolling: neutral (313 us); co-bound kernel.
// R7: fp16 intermediates, fp32 arithmetic unchanged: global ping-pong fp16 (HBM/2),
//     LDS B packed fp16 (LDS 45.5K -> 34K -> 4 blocks/CU, 16 waves), APITCH 84->80.
// R8: fix cvt_pkrtz return-type mismatch (__fp16 vec2, not _Float16 vec2).

#define H 512
#define W 512
#define IMG (H * W)
#define NIMG 64
#define NPRED 32

#define APITCH 80   // fp32 floats: 20 quads; c=0 pad, c=1..18 data (gx = tileX+4c-8), c=19 pad
#define AROWS 74    // row r <-> gy = tileY + r - 4; data r 0..71, r 72,73 pad
#define BP2 38      // B row pitch in uints (2 fp16 cols per uint); 36 data + 2 pad
#define BROWS 68    // row br <-> gy = tileY + br - 2; col: uint u <-> tile cols 2u-4, 2u-3

typedef _Float16 f16;
typedef __fp16 fp16v2 __attribute__((ext_vector_type(2)));

__device__ __forceinline__ float2 unpack2(uint u) {
    fp16v2 h = __builtin_bit_cast(fp16v2, u);
    return make_float2((float)h.x, (float)h.y);
}
__device__ __forceinline__ uint pack2(float a, float b) {
    fp16v2 h = __builtin_amdgcn_cvt_pkrtz(a, b);
    return __builtin_bit_cast(uint, h);
}

__device__ __forceinline__ float wsum64(float v) {
#pragma unroll
    for (int o = 32; o > 0; o >>= 1) v += __shfl_down(v, o);
    return v;
}

// fp32 hmin (3-wide row min) for 6 positions from LDS A; 3 aligned b128 reads.
// Also returns center quad for register reuse.
__device__ __forceinline__ void hmin3(const float* __restrict__ row, float h[6],
                                      float4& q1out) {
    float4 q0 = *(const float4*)(row);
    float4 q1 = *(const float4*)(row + 4);
    float4 q2 = *(const float4*)(row + 8);
    q1out = q1;
    h[0] = fminf(q0.z, fminf(q0.w, q1.x));
    h[1] = fminf(q0.w, fminf(q1.x, q1.y));
    h[2] = fminf(q1.x, fminf(q1.y, q1.z));
    h[3] = fminf(q1.y, fminf(q1.z, q1.w));
    h[4] = fminf(q1.z, fminf(q1.w, q2.x));
    h[5] = fminf(q1.w, fminf(q2.x, q2.y));
}

// fp16-packed hmin from LDS B: 3x ds_read_b64 + unpacks; row points at uint of col c-4.
__device__ __forceinline__ void hmin3h(const uint* __restrict__ row, float h[6],
                                       float4& q1out) {
    uint2 a = *(const uint2*)(row);       // cols c-4..c-1
    uint2 b = *(const uint2*)(row + 2);   // cols c..c+3
    uint2 d = *(const uint2*)(row + 4);   // cols c+4..c+7
    float2 p1 = unpack2(a.y);             // c-2, c-1
    float2 p2 = unpack2(b.x);             // c,   c+1
    float2 p3 = unpack2(b.y);             // c+2, c+3
    float2 p4 = unpack2(d.x);             // c+4, c+5
    q1out = make_float4(p2.x, p2.y, p3.x, p3.y);
    h[0] = fminf(p1.x, fminf(p1.y, p2.x));
    h[1] = fminf(p1.y, fminf(p2.x, p2.y));
    h[2] = fminf(p2.x, fminf(p2.y, p3.x));
    h[3] = fminf(p2.y, fminf(p3.x, p3.y));
    h[4] = fminf(p3.x, fminf(p3.y, p4.x));
    h[5] = fminf(p3.y, fminf(p4.x, p4.y));
}

__device__ __forceinline__ void erode1(const float a[6], const float b[6], const float c[6],
                                       bool rowok, const bool cm[6], float e[6]) {
#pragma unroll
    for (int j = 0; j < 6; j++) {
        float v = fminf(a[j], fminf(b[j], c[j]));
        e[j] = (rowok && cm[j]) ? v : -INFINITY;
    }
}

__device__ __forceinline__ void erode2(const float a[6], const float b[6], const float c[6],
                                       int gy, bool lo, bool ro, float e[6]) {
    bool oob = (gy < 0) || (gy >= H);
#pragma unroll
    for (int j = 0; j < 6; j++) {
        float v = fminf(a[j], fminf(b[j], c[j]));
        e[j] = oob ? -INFINITY : v;
    }
    if (lo) e[0] = -INFINITY;
    if (ro) e[5] = -INFINITY;
}

__device__ __forceinline__ void hmax1(const float e[6], float hx[4], float ec[4]) {
    hx[0] = fmaxf(e[0], fmaxf(e[1], e[2]));
    hx[1] = fmaxf(e[1], fmaxf(e[2], e[3]));
    hx[2] = fmaxf(e[2], fmaxf(e[3], e[4]));
    hx[3] = fmaxf(e[3], fmaxf(e[4], e[5]));
    ec[0] = e[1]; ec[1] = e[2]; ec[2] = e[3]; ec[3] = e[4];
}

// Fill LDS A (fp32) from fp32 source; non-data / out-of-image = +inf.
template<int SIG>
__device__ void fillA_f32(float* __restrict__ A, const float* __restrict__ src,
                          int tileX, int tileY, int tid) {
    const float PINF = INFINITY;
    for (int it = tid; it < AROWS * 20; it += 256) {
        int r = it / 20;
        int c = it - r * 20;
        int gy = tileY + r - 4;
        int gx = tileX + 4 * c - 8;
        float4 v = make_float4(PINF, PINF, PINF, PINF);
        if ((unsigned)(c - 1) < 18u && (unsigned)gy < (unsigned)H &&
            (unsigned)gx < (unsigned)W) {
            v = *(const float4*)(src + (size_t)gy * W + gx);
            if (SIG) {
                v.x = 1.0f / (1.0f + __expf(-v.x));
                v.y = 1.0f / (1.0f + __expf(-v.y));
                v.z = 1.0f / (1.0f + __expf(-v.z));
                v.w = 1.0f / (1.0f + __expf(-v.w));
            }
        }
        *(float4*)(A + r * APITCH + 4 * c) = v;
    }
}

// Fill LDS A (fp32) from fp16 source.
__device__ void fillA_f16(float* __restrict__ A, const f16* __restrict__ src,
                          int tileX, int tileY, int tid) {
    const float PINF = INFINITY;
    for (int it = tid; it < AROWS * 20; it += 256) {
        int r = it / 20;
        int c = it - r * 20;
        int gy = tileY + r - 4;
        int gx = tileX + 4 * c - 8;
        float4 v = make_float4(PINF, PINF, PINF, PINF);
        if ((unsigned)(c - 1) < 18u && (unsigned)gy < (unsigned)H &&
            (unsigned)gx < (unsigned)W) {
            uint2 g = *(const uint2*)(src + (size_t)gy * W + gx);
            float2 lo = unpack2(g.x), hi = unpack2(g.y);
            v = make_float4(lo.x, lo.y, hi.x, hi.y);
        }
        *(float4*)(A + r * APITCH + 4 * c) = v;
    }
}

// Stage 1: one skeletonize iteration A(fp32) -> B(fp16 packed).
// 252 items = 14 strips(5 rows) x 18 quads; br >= 68 skipped.
__device__ void stage1(const float* __restrict__ A, uint* __restrict__ Bu,
                       int tileX, int tileY, int tid) {
    for (int item = tid; item < 252; item += 256) {
        const int s = item / 18;
        const int q = item - s * 18;
        const int gcb = tileX - 4 + 4 * q;
        const int ys = tileY - 2 + 5 * s;
        bool cm[6], sm[4];
#pragma unroll
        for (int j = 0; j < 6; j++) cm[j] = ((unsigned)(gcb - 1 + j) < (unsigned)W);
#pragma unroll
        for (int j = 0; j < 4; j++) sm[j] = ((unsigned)(gcb + j) < (unsigned)W);
        const int lr = 5 * s + 2;
        const float* Ab = A + 4 * q;
        float hm[3][6], hx[3][4], e[6], ec_cur[4], ec_nxt[4];
        float4 scq[3], qd;
        hmin3(Ab + (lr - 2) * APITCH, hm[0], qd);
        hmin3(Ab + (lr - 1) * APITCH, hm[1], qd);
        hmin3(Ab + (lr + 0) * APITCH, hm[2], scq[0]);
        erode1(hm[0], hm[1], hm[2], (unsigned)(ys - 1) < (unsigned)H, cm, e);
        hmax1(e, hx[0], ec_nxt);
        hmin3(Ab + (lr + 1) * APITCH, hm[0], scq[1]);
        erode1(hm[1], hm[2], hm[0], (unsigned)ys < (unsigned)H, cm, e);
        hmax1(e, hx[1], ec_cur);
#pragma unroll
        for (int k = 0; k < 5; k++) {
            hmin3(Ab + (lr + 2 + k) * APITCH, hm[(k + 1) % 3], scq[(2 + k) % 3]);
            erode1(hm[(k + 2) % 3], hm[k % 3], hm[(k + 1) % 3],
                   (unsigned)(ys + k + 1) < (unsigned)H, cm, e);
            hmax1(e, hx[(k + 2) % 3], ec_nxt);
            float t0 = fmaxf(hx[k % 3][0], fmaxf(hx[(k + 1) % 3][0], hx[(k + 2) % 3][0]));
            float t1 = fmaxf(hx[k % 3][1], fmaxf(hx[(k + 1) % 3][1], hx[(k + 2) % 3][1]));
            float t2 = fmaxf(hx[k % 3][2], fmaxf(hx[(k + 1) % 3][2], hx[(k + 2) % 3][2]));
            float t3 = fmaxf(hx[k % 3][3], fmaxf(hx[(k + 1) % 3][3], hx[(k + 2) % 3][3]));
            float4 sc = scq[k % 3];
            float o0 = fminf(fmaxf(sc.x - (sc.x - ec_cur[0]) * t0, 0.0f), 1.0f);
            float o1 = fminf(fmaxf(sc.y - (sc.y - ec_cur[1]) * t1, 0.0f), 1.0f);
            float o2 = fminf(fmaxf(sc.z - (sc.z - ec_cur[2]) * t2, 0.0f), 1.0f);
            float o3 = fminf(fmaxf(sc.w - (sc.w - ec_cur[3]) * t3, 0.0f), 1.0f);
            int br = 5 * s + k;
            if (br < BROWS) {
                bool rin = ((unsigned)(ys + k) < (unsigned)H);
                float v0 = (rin && sm[0]) ? o0 : INFINITY;  // +inf: erosion-neutral pad
                float v1 = (rin && sm[1]) ? o1 : INFINITY;
                float v2 = (rin && sm[2]) ? o2 : INFINITY;
                float v3 = (rin && sm[3]) ? o3 : INFINITY;
                uint2 wv;
                wv.x = pack2(v0, v1);
                wv.y = pack2(v2, v3);
                *(uint2*)(Bu + br * BP2 + 2 * q) = wv;
            }
            ec_cur[0] = ec_nxt[0]; ec_cur[1] = ec_nxt[1];
            ec_cur[2] = ec_nxt[2]; ec_cur[3] = ec_nxt[3];
        }
    }
}

// Stage 2: second iteration B(fp16) -> interior 64x64 (fp16 global or fp32 regs).
// 256 threads: 16 col-quads x 16 4-row strips.
template<bool TOREG>
__device__ void stage2(const uint* __restrict__ Bu, int tileX, int tileY,
                       int tx, int ty, f16* __restrict__ gdst, float (*oreg)[4]) {
    const int X = tileX + 4 * tx;
    const int gy0 = tileY + 4 * ty;
    const int rb = 4 * ty + 2;
    const bool lo = (X == 0);
    const bool ro = (X + 4 >= W);
    const uint* Bb = Bu + 2 * tx;          // uint of tile-col 4tx-4
    float hm[3][6], hx[3][4], e[6], ec_cur[4], ec_nxt[4];
    float4 scq[3], qd;
    hmin3h(Bb + (rb - 2) * BP2, hm[0], qd);
    hmin3h(Bb + (rb - 1) * BP2, hm[1], qd);
    hmin3h(Bb + (rb + 0) * BP2, hm[2], scq[0]);
    erode2(hm[0], hm[1], hm[2], gy0 - 1, lo, ro, e);
    hmax1(e, hx[0], ec_nxt);
    hmin3h(Bb + (rb + 1) * BP2, hm[0], scq[1]);
    erode2(hm[1], hm[2], hm[0], gy0, lo, ro, e);
    hmax1(e, hx[1], ec_cur);
#pragma unroll
    for (int k = 0; k < 4; k++) {
        hmin3h(Bb + (rb + 2 + k) * BP2, hm[(k + 1) % 3], scq[(2 + k) % 3]);
        erode2(hm[(k + 2) % 3], hm[k % 3], hm[(k + 1) % 3], gy0 + k + 1, lo, ro, e);
        hmax1(e, hx[(k + 2) % 3], ec_nxt);
        float t0 = fmaxf(hx[k % 3][0], fmaxf(hx[(k + 1) % 3][0], hx[(k + 2) % 3][0]));
        float t1 = fmaxf(hx[k % 3][1], fmaxf(hx[(k + 1) % 3][1], hx[(k + 2) % 3][1]));
        float t2 = fmaxf(hx[k % 3][2], fmaxf(hx[(k + 1) % 3][2], hx[(k + 2) % 3][2]));
        float t3 = fmaxf(hx[k % 3][3], fmaxf(hx[(k + 1) % 3][3], hx[(k + 2) % 3][3]));
        float4 sc = scq[k % 3];
        float4 o;
        o.x = fminf(fmaxf(sc.x - (sc.x - ec_cur[0]) * t0, 0.0f), 1.0f);
        o.y = fminf(fmaxf(sc.y - (sc.y - ec_cur[1]) * t1, 0.0f), 1.0f);
        o.z = fminf(fmaxf(sc.z - (sc.z - ec_cur[2]) * t2, 0.0f), 1.0f);
        o.w = fminf(fmaxf(sc.w - (sc.w - ec_cur[3]) * t3, 0.0f), 1.0f);
        if (TOREG) {
            oreg[k][0] = o.x; oreg[k][1] = o.y; oreg[k][2] = o.z; oreg[k][3] = o.w;
        } else {
            uint2 w;
            w.x = pack2(o.x, o.y);
            w.y = pack2(o.z, o.w);
            *(uint2*)(gdst + (size_t)(gy0 + k) * W + X) = w;
        }
        ec_cur[0] = ec_nxt[0]; ec_cur[1] = ec_nxt[1];
        ec_cur[2] = ec_nxt[2]; ec_cur[3] = ec_nxt[3];
    }
}

// ---- K1: sigmoid + dice partials + iters 1,2 ----
__global__ __launch_bounds__(256, 4) void k_first(
    const float* __restrict__ logits, const float* __restrict__ target,
    f16* __restrict__ outb, float* __restrict__ parts0, float* __restrict__ parts1) {
    __shared__ float A[AROWS * APITCH];
    __shared__ uint Bu[BROWS * BP2];
    __shared__ float red[8];
    const int img = blockIdx.z;
    const int tileX = blockIdx.x * 64, tileY = blockIdx.y * 64;
    const int tid = threadIdx.y * 16 + threadIdx.x;
    const bool pred = (img < NPRED);
    if (pred) fillA_f32<1>(A, logits + (size_t)img * IMG, tileX, tileY, tid);
    else      fillA_f32<0>(A, target + (size_t)(img - NPRED) * IMG, tileX, tileY, tid);
    __syncthreads();
    float a = 0.0f, b = 0.0f;
    if (pred) {
        const float* tgt = target + (size_t)img * IMG;
        for (int i = tid; i < 1024; i += 256) {
            int r = i >> 4, c4 = (i & 15) * 4;
            float4 p = *(const float4*)(A + (r + 4) * APITCH + c4 + 8);
            float4 t = *(const float4*)(tgt + (size_t)(tileY + r) * W + tileX + c4);
            a += p.x * t.x + p.y * t.y + p.z * t.z + p.w * t.w;
            b += p.x + p.y + p.z + p.w;
        }
    } else {
        for (int i = tid; i < 1024; i += 256) {
            int r = i >> 4, c4 = (i & 15) * 4;
            float4 t = *(const float4*)(A + (r + 4) * APITCH + c4 + 8);
            a += t.x + t.y + t.z + t.w;
        }
    }
    a = wsum64(a); b = wsum64(b);
    if ((tid & 63) == 0) { red[tid >> 6] = a; red[4 + (tid >> 6)] = b; }
    stage1(A, Bu, tileX, tileY, tid);
    __syncthreads();
    if (tid == 0) {
        int bi = blockIdx.z * 64 + blockIdx.y * 8 + blockIdx.x;
        parts0[bi] = red[0] + red[1] + red[2] + red[3];
        parts1[bi] = red[4] + red[5] + red[6] + red[7];
    }
    stage2<false>(Bu, tileX, tileY, threadIdx.x, threadIdx.y,
                  outb + (size_t)img * IMG, nullptr);
}

// ---- K2..K4: two iterations, fp16 buf -> fp16 buf ----
__global__ __launch_bounds__(256, 4) void k_mid(
    const f16* __restrict__ in, f16* __restrict__ outb) {
    __shared__ float A[AROWS * APITCH];
    __shared__ uint Bu[BROWS * BP2];
    const int img = blockIdx.z;
    const int tileX = blockIdx.x * 64, tileY = blockIdx.y * 64;
    const int tid = threadIdx.y * 16 + threadIdx.x;
    fillA_f16(A, in + (size_t)img * IMG, tileX, tileY, tid);
    __syncthreads();
    stage1(A, Bu, tileX, tileY, tid);
    __syncthreads();
    stage2<false>(Bu, tileX, tileY, threadIdx.x, threadIdx.y,
                  outb + (size_t)img * IMG, nullptr);
}

// ---- K5: iters 9,10 for pred tile AND matching target tile; skel-dice partials ----
__global__ __launch_bounds__(256, 4) void k_last(
    const f16* __restrict__ in, float* __restrict__ pA,
    float* __restrict__ pB, float* __restrict__ pC) {
    __shared__ float A[AROWS * APITCH];
    __shared__ uint Bu[BROWS * BP2];
    __shared__ float red[12];
    const int img = blockIdx.z;                  // 0..31
    const int tileX = blockIdx.x * 64, tileY = blockIdx.y * 64;
    const int tid = threadIdx.y * 16 + threadIdx.x;
    float op[4][4], ot[4][4];
    fillA_f16(A, in + (size_t)img * IMG, tileX, tileY, tid);
    __syncthreads();
    stage1(A, Bu, tileX, tileY, tid);
    __syncthreads();
    stage2<true>(Bu, tileX, tileY, threadIdx.x, threadIdx.y, nullptr, op);
    fillA_f16(A, in + (size_t)(img + NPRED) * IMG, tileX, tileY, tid);
    __syncthreads();   // all threads past stage2 B-reads before stage1 rewrites B
    stage1(A, Bu, tileX, tileY, tid);
    __syncthreads();
    stage2<true>(Bu, tileX, tileY, threadIdx.x, threadIdx.y, nullptr, ot);
    float a = 0.0f, b = 0.0f, c = 0.0f;
#pragma unroll
    for (int k = 0; k < 4; k++)
#pragma unroll
        for (int j = 0; j < 4; j++) {
            a += op[k][j] * ot[k][j];
            b += op[k][j];
            c += ot[k][j];
        }
    a = wsum64(a); b = wsum64(b); c = wsum64(c);
    if ((tid & 63) == 0) {
        red[tid >> 6] = a; red[4 + (tid >> 6)] = b; red[8 + (tid >> 6)] = c;
    }
    __syncthreads();
    if (tid == 0) {
        int bi = img * 64 + blockIdx.y * 8 + blockIdx.x;
        pA[bi] = red[0] + red[1] + red[2] + red[3];
        pB[bi] = red[4] + red[5] + red[6] + red[7];
        pC[bi] = red[8] + red[9] + red[10] + red[11];
    }
}

// ---- per-image dice from 64 tile partials (1 wave per image) ----
__global__ __launch_bounds__(64) void finalize_img(
    const float* __restrict__ parts0, const float* __restrict__ parts1,
    const float* __restrict__ pA, const float* __restrict__ pB,
    const float* __restrict__ pC, float* __restrict__ dices) {
    const int i = blockIdx.x, t = threadIdx.x;
    float inter = wsum64(parts0[i * 64 + t]);
    float sp = wsum64(parts1[i * 64 + t]);
    float st = wsum64(parts0[(NPRED + i) * 64 + t]);
    float i2 = wsum64(pA[i * 64 + t]);
    float sp2 = wsum64(pB[i * 64 + t]);
    float st2 = wsum64(pC[i * 64 + t]);
    if (t == 0) {
        dices[i] = (float)((2.0 * (double)inter + 1e-5) / ((double)sp + (double)st + 1e-5));
        dices[32 + i] = (float)((2.0 * (double)i2 + 1e-5) / ((double)sp2 + (double)st2 + 1e-5));
    }
}

__global__ void finalize_out(const float* __restrict__ dices, float* __restrict__ out) {
    const int t = threadIdx.x;
    double d = 0.0, sd = 0.0;
    if (t < 32) { d = dices[t]; sd = dices[32 + t]; }
#pragma unroll
    for (int o = 32; o > 0; o >>= 1) { d += __shfl_down(d, o); sd += __shfl_down(sd, o); }
    if (t == 0) {
        d *= (1.0 / 32.0); sd *= (1.0 / 32.0);
        out[0] = (float)(0.5 * (1.0 - d) + 0.5 * (1.0 - sd));
        out[1] = (float)d;
        out[2] = (float)sd;
    }
}

extern "C" void kernel_launch(void* const* d_in, const int* in_sizes, int n_in,
                              void* d_out, int out_size, void* d_ws, size_t ws_size,
                              hipStream_t stream) {
    (void)in_sizes; (void)n_in; (void)out_size; (void)ws_size;
    const float* logits = (const float*)d_in[0];
    const float* target = (const float*)d_in[1];
    float* out = (float*)d_out;
    f16* buf0 = (f16*)d_ws;                         // 64*262144 halves (33.5 MB)
    f16* buf1 = buf0 + (size_t)NIMG * IMG;
    float* parts0 = (float*)(buf1 + (size_t)NIMG * IMG);   // 4096
    float* parts1 = parts0 + 4096;                  // 4096
    float* pA = parts1 + 4096;                      // 2048
    float* pB = pA + 2048;
    float* pC = pB + 2048;
    float* dices = pC + 2048;                       // 64

    dim3 blk(16, 16, 1);
    k_first<<<dim3(8, 8, NIMG), blk, 0, stream>>>(logits, target, buf0, parts0, parts1);
    k_mid<<<dim3(8, 8, NIMG), blk, 0, stream>>>(buf0, buf1);   // iters 3,4
    k_mid<<<dim3(8, 8, NIMG), blk, 0, stream>>>(buf1, buf0);   // iters 5,6
    k_mid<<<dim3(8, 8, NIMG), blk, 0, stream>>>(buf0, buf1);   // iters 7,8
    k_last<<<dim3(8, 8, NPRED), blk, 0, stream>>>(buf1, pA, pB, pC);  // iters 9,10 + partials
    finalize_img<<<32, 64, 0, stream>>>(parts0, parts1, pA, pB, pC, dices);
    finalize_out<<<1, 64, 0, stream>>>(dices, out);
}